// Round 9
// baseline (1106.601 us; speedup 1.0000x reference)
//
#include <hip/hip_runtime.h>
#include <stdint.h>

#define Bb 128
#define Nn 1024
#define Dd 512
#define Ss 64

constexpr float kScale = 0.044194173824159216f;  // 512^-0.5
constexpr float kEps = 1e-8f;

typedef __bf16 bf16x8 __attribute__((ext_vector_type(8)));
typedef float f32x4 __attribute__((ext_vector_type(4)));
typedef float f32x16 __attribute__((ext_vector_type(16)));

#define MFMA32 __builtin_amdgcn_mfma_f32_32x32x16_bf16

__device__ inline unsigned short f2bf_rne(float x) {
  unsigned u = __builtin_bit_cast(unsigned, x);
  u += 0x7FFFu + ((u >> 16) & 1u);
  return (unsigned short)(u >> 16);
}
__device__ inline float bf2f(unsigned short h) {
  unsigned u = ((unsigned)h) << 16;
  return __builtin_bit_cast(float, u);
}

// async global->LDS, 16B per lane; LDS dest must be wave-uniform base (HW adds lane*16)
__device__ inline void gl_lds16(const void* g, void* l) {
  typedef unsigned int u32;
  auto gp = (u32 __attribute__((address_space(1)))*)(unsigned long long)(uintptr_t)g;
  auto lp = (u32 __attribute__((address_space(3)))*)(unsigned int)(uintptr_t)l;
  __builtin_amdgcn_global_load_lds(gp, lp, 16, 0, 0);
}

// f32 -> bf16 hi/lo split (a ~= hi + lo, residual ~2^-16 rel)
__global__ void cast_split(const float* __restrict__ in,
                           unsigned short* __restrict__ hi,
                           unsigned short* __restrict__ lo,
                           int n4) {
  int i = blockIdx.x * blockDim.x + threadIdx.x;
  const int stride = gridDim.x * blockDim.x;
  for (; i < n4; i += stride) {
    const float4 v = ((const float4*)in)[i];
    ushort4 h, lw;
    h.x = f2bf_rne(v.x); lw.x = f2bf_rne(v.x - bf2f(h.x));
    h.y = f2bf_rne(v.y); lw.y = f2bf_rne(v.y - bf2f(h.y));
    h.z = f2bf_rne(v.z); lw.z = f2bf_rne(v.z - bf2f(h.z));
    h.w = f2bf_rne(v.w); lw.w = f2bf_rne(v.w - bf2f(h.w));
    ((ushort4*)hi)[i] = h;
    ((ushort4*)lo)[i] = lw;
  }
}

// C[M,512] = act(A[M,512] @ W[512,512]^T + bias), FUSED 3-term split bf16.
// BM=BN=256, 8 waves (2Mx4N), wave-tile 128x64, 32x32x16 MFMA, K-half = 16.
// Ring-4 x 32KB LDS (half = Ah[256][16]|Al|Wh[256][16]|Wl, 8KB each).
// Schedule (T3+T4+T2+T5), per half h — ORDER MATTERS (R8 race fix):
//   lgkmcnt(0); sched_bar;      <- frags(h) in regs; buffer-(h%4) reads done
//   vmcnt(counted);             <- MY stage(h+1) writes landed   [BEFORE barrier]
//   s_barrier;                  <- collective: everyone's stage(h+1) landed,
//                                  everyone done reading buffer h%4
//   STG(h+4) [4 gl_lds]; READF(h+1)->other reg set [12 ds_read]; sched_bar;
//   setprio(1); 24 MFMA on frags(h); setprio(0);   <- reads drain under MFMA
// Swizzle: stored granule p = g ^ ((row>>2)&1); staging source g=(l&1)^((l>>3)&1).
template <int ACT>
__global__ __launch_bounds__(512, 1) void gemm_hp(
    const unsigned short* __restrict__ Ah, const unsigned short* __restrict__ Al,
    const unsigned short* __restrict__ Wh, const unsigned short* __restrict__ Wl,
    const float* __restrict__ bias,
    unsigned short* __restrict__ Ch, unsigned short* __restrict__ Cl) {
  constexpr int NH = 32;  // K=512 / 16
  extern __shared__ unsigned short lds[];  // 4 x 16384 ushorts = 128KB
  const int t = threadIdx.x, l = t & 63, w = t >> 6;
  const int wr = w >> 2, wc = w & 3;

  // bijective XCD-chunked swizzle (1024 = 8 x 128); wg pairs share the A panel
  const int wg = ((blockIdx.x & 7) << 7) + (blockIdx.x >> 3);
  const long rowA0 = (long)(wg >> 1) * 256;
  const int colB0 = (wg & 1) * 256;

  // ---- staging: 32 x 1KB chunks per half (32 rows x 32B each); 4 per wave,
  // all 4 from ONE array (wave w -> array w>>1: Ah,Al,Wh,Wl) ----
  const unsigned short* sbase =
      (w < 4) ? ((w < 2) ? Ah + rowA0 * 512 : Al + rowA0 * 512)
              : ((w < 6) ? Wh + (long)colB0 * 512 : Wl + (long)colB0 * 512);
  const int lcb = (w & 1) * 4;                  // local chunk base (0 or 4)
  const int gsw = (l & 1) ^ ((l >> 3) & 1);     // inverse-swizzled source granule
  const unsigned short* src0 = sbase + (lcb * 32 + (l >> 1)) * 512 + gsw * 8;
  const int dst0 = (w >> 1) * 4096 + lcb * 512; // wave-uniform LDS chunk base

#define STG(h)                                                            \
  {                                                                       \
    unsigned short* bq_ = lds + ((h) & 3) * 16384;                        \
    _Pragma("unroll") for (int j = 0; j < 4; j++)                         \
        gl_lds16(src0 + j * 16384 + (h) * 16, bq_ + dst0 + j * 512);      \
  }

  // ---- frag read bases (ushort units). row = R0 + (l&31), granule g = l>>5,
  // stored pos p = g ^ ((row>>2)&1) = (l>>5) ^ ((l>>2)&1). ----
  const int p8 = ((l >> 5) ^ ((l >> 2) & 1)) * 8;
  const int abase0 = (wr * 128 + (l & 31)) * 16 + p8;           // Ah@0, Al@+4096
  const int bbase0 = 8192 + (wc * 64 + (l & 31)) * 16 + p8;     // Wh@8192, Wl@+4096

#define READF(h, S)                                                       \
  {                                                                       \
    const unsigned short* bq_ = lds + ((h) & 3) * 16384;                  \
    _Pragma("unroll") for (int m = 0; m < 4; m++) {                       \
      ah##S[m] = *(const bf16x8*)(bq_ + abase0 + m * 512);                \
      al##S[m] = *(const bf16x8*)(bq_ + 4096 + abase0 + m * 512);         \
    }                                                                     \
    _Pragma("unroll") for (int n = 0; n < 2; n++) {                       \
      bh##S[n] = *(const bf16x8*)(bq_ + bbase0 + n * 512);                \
      bl##S[n] = *(const bf16x8*)(bq_ + 4096 + bbase0 + n * 512);         \
    }                                                                     \
  }

#define MFMACL(S)                                                         \
  {                                                                       \
    _Pragma("unroll") for (int m = 0; m < 4; m++)                         \
        _Pragma("unroll") for (int n = 0; n < 2; n++) {                   \
      acc[m][n] = MFMA32(ah##S[m], bh##S[n], acc[m][n], 0, 0, 0);         \
      acc[m][n] = MFMA32(al##S[m], bh##S[n], acc[m][n], 0, 0, 0);         \
      acc[m][n] = MFMA32(ah##S[m], bl##S[n], acc[m][n], 0, 0, 0);         \
    }                                                                     \
  }

#define BODY(h, CUR, NXT)                                                 \
  {                                                                       \
    asm volatile("s_waitcnt lgkmcnt(0)" ::: "memory");                    \
    __builtin_amdgcn_sched_barrier(0);                                    \
    if ((h) < 29) {                                                       \
      asm volatile("s_waitcnt vmcnt(8)" ::: "memory");                    \
    } else if ((h) == 29) {                                               \
      asm volatile("s_waitcnt vmcnt(4)" ::: "memory");                    \
    } else if ((h) == 30) {                                               \
      asm volatile("s_waitcnt vmcnt(0)" ::: "memory");                    \
    }                                                                     \
    __builtin_amdgcn_s_barrier();                                         \
    if ((h) + 4 < NH) STG((h) + 4);                                       \
    if ((h) + 1 < NH) READF((h) + 1, NXT);                                \
    __builtin_amdgcn_sched_barrier(0);                                    \
    __builtin_amdgcn_s_setprio(1);                                        \
    MFMACL(CUR);                                                          \
    __builtin_amdgcn_s_setprio(0);                                        \
  }

  f32x16 acc[4][2] = {};
  bf16x8 ahA[4], alA[4], bhA[2], blA[2];
  bf16x8 ahB[4], alB[4], bhB[2], blB[2];

  STG(0); STG(1); STG(2); STG(3);
  asm volatile("s_waitcnt vmcnt(12)" ::: "memory");  // stage(0) landed (own 4)
  __builtin_amdgcn_s_barrier();                      // everyone's stage(0) landed
  READF(0, A);

  for (int hh = 0; hh < NH; hh += 2) {
    BODY(hh, A, B);
    BODY(hh + 1, B, A);
  }
#undef STG
#undef READF
#undef MFMACL
#undef BODY

  // epilogue: C/D 32x32 layout: col = l&31, row = (r&3) + 8*(r>>2) + 4*(l>>5)
#pragma unroll
  for (int m = 0; m < 4; m++)
#pragma unroll
    for (int n = 0; n < 2; n++) {
      const int col = colB0 + wc * 64 + n * 32 + (l & 31);
      const float bv = bias[col];
#pragma unroll
      for (int r = 0; r < 16; r++) {
        const long row = rowA0 + wr * 128 + m * 32 + (r & 3) + 8 * (r >> 2) + 4 * (l >> 5);
        float xv = acc[m][n][r] + bv;
        if (ACT) xv = fmaxf(xv, 0.0f);
        const unsigned short h = f2bf_rne(xv);
        const long idx = row * 512 + col;
        Ch[idx] = h;
        Cl[idx] = f2bf_rne(xv - bf2f(h));
      }
    }
}

// dots[b,64,1024] = scale * slots[64,512] @ k[b,1024,512]^T  (split bf16 MFMA, f32 out)
__global__ __launch_bounds__(256) void gemm_dots_split(
    const unsigned short* __restrict__ Qh, const unsigned short* __restrict__ Ql,
    const unsigned short* __restrict__ Kh, const unsigned short* __restrict__ Kl,
    float* __restrict__ dots) {
  constexpr int K = 512, BM = 64, BN = 128, BK = 32;
  __shared__ __align__(16) unsigned short lah[BM * BK];
  __shared__ __align__(16) unsigned short lal[BM * BK];
  __shared__ __align__(16) unsigned short lbh[BN * BK];
  __shared__ __align__(16) unsigned short lbl[BN * BK];
  const int t = threadIdx.x, l = t & 63, w = t >> 6;
  const int b = blockIdx.x >> 3, bc = blockIdx.x & 7;
  const unsigned short* kh = Kh + (long)b * Nn * Dd;
  const unsigned short* kl = Kl + (long)b * Nn * Dd;
  f32x4 acc[4][2] = {};

  for (int k0 = 0; k0 < K; k0 += BK) {
    {
      const int c = t;
      const int ga = (c >> 2) * K + k0 + (c & 3) * 8;
      const int lo = (w * 64) * 8;
      gl_lds16(Qh + ga, lah + lo);
      gl_lds16(Ql + ga, lal + lo);
    }
#pragma unroll
    for (int qq = 0; qq < 2; qq++) {
      const int c = qq * 256 + t;
      const long gb = (long)(bc * BN + (c >> 2)) * K + k0 + (c & 3) * 8;
      const int lo = (qq * 256 + w * 64) * 8;
      gl_lds16(kh + gb, lbh + lo);
      gl_lds16(kl + gb, lbl + lo);
    }
    __syncthreads();
    bf16x8 ah[4], al[4], bh[2], bl[2];
#pragma unroll
    for (int m = 0; m < 4; m++) {
      const int off = (m * 16 + (l & 15)) * BK + (l >> 4) * 8;
      ah[m] = *(const bf16x8*)(lah + off);
      al[m] = *(const bf16x8*)(lal + off);
    }
#pragma unroll
    for (int n = 0; n < 2; n++) {
      const int off = (w * 32 + n * 16 + (l & 15)) * BK + (l >> 4) * 8;
      bh[n] = *(const bf16x8*)(lbh + off);
      bl[n] = *(const bf16x8*)(lbl + off);
    }
#pragma unroll
    for (int m = 0; m < 4; m++)
#pragma unroll
      for (int n = 0; n < 2; n++) {
        acc[m][n] = __builtin_amdgcn_mfma_f32_16x16x32_bf16(ah[m], bh[n], acc[m][n], 0, 0, 0);
        acc[m][n] = __builtin_amdgcn_mfma_f32_16x16x32_bf16(al[m], bh[n], acc[m][n], 0, 0, 0);
        acc[m][n] = __builtin_amdgcn_mfma_f32_16x16x32_bf16(ah[m], bl[n], acc[m][n], 0, 0, 0);
      }
    __syncthreads();
  }
  float* dp = dots + (long)b * Ss * Nn;
#pragma unroll
  for (int m = 0; m < 4; m++) {
    const int row = m * 16 + (l >> 4) * 4;
#pragma unroll
    for (int n = 0; n < 2; n++) {
      const int col = bc * BN + w * 32 + n * 16 + (l & 15);
#pragma unroll
      for (int r = 0; r < 4; r++) dp[(long)(row + r) * Nn + col] = acc[m][n][r] * kScale;
    }
  }
}

// per-batch: s_j[b,i] = sum_j dots, s_all[b] = sum_ij dots
__global__ __launch_bounds__(256) void reduce_k(
    const float* __restrict__ dots, float* __restrict__ s_j, float* __restrict__ s_all) {
  const int b = blockIdx.x;
  const int t = threadIdx.x;
  const float* dp = dots + (long)b * Ss * Nn;
  const int i = t >> 2, qq = t & 3;
  float s = 0.f;
  const float* rp = dp + i * Nn + qq * 256;
  for (int j = 0; j < 256; j++) s += rp[j];
  __shared__ float part[256];
  __shared__ float rowsum[64];
  part[t] = s;
  __syncthreads();
  if (t < 64) {
    const float v = part[t * 4] + part[t * 4 + 1] + part[t * 4 + 2] + part[t * 4 + 3];
    rowsum[t] = v;
    s_j[b * 64 + t] = v;
  }
  __syncthreads();
  if (t == 0) {
    float tot = 0.f;
    for (int k = 0; k < 64; k++) tot += rowsum[k];
    s_all[b] = tot;
  }
}

// attn = sigmoid(dots * s_all/s_j) -> out; inv_r = 1/(rowsum(attn)+eps)
__global__ __launch_bounds__(256) void attn_k(
    const float* __restrict__ dots, const float* __restrict__ s_j,
    const float* __restrict__ s_all, float* __restrict__ attn_out,
    float* __restrict__ inv_r) {
  const int bi = blockIdx.x;
  const int b = bi >> 6;
  const int t = threadIdx.x;
  const float ratio = s_all[b] / s_j[bi];
  const float* dp = dots + (long)bi * Nn;
  float* ap = attn_out + (long)bi * Nn;
  float s = 0.f;
#pragma unroll
  for (int qq = 0; qq < 4; qq++) {
    const int j = qq * 256 + t;
    const float x = dp[j] * ratio;
    const float a = 1.f / (1.f + expf(-x));
    ap[j] = a;
    s += a;
  }
  __shared__ float red[256];
  red[t] = s;
  __syncthreads();
  for (int off = 128; off > 0; off >>= 1) {
    if (t < off) red[t] += red[t + off];
    __syncthreads();
  }
  if (t == 0) inv_r[bi] = 1.f / (red[0] + kEps);
}

// updates[b,i,d] = inv_r[b,i] * sum_j attn[b,i,j] * inputs[b,j,d]  (fp32 register tile)
__global__ __launch_bounds__(256, 1) void updates_k2(
    const float* __restrict__ attn, const float* __restrict__ inputs,
    const float* __restrict__ inv_r, float* __restrict__ out0) {
  constexpr int NT2 = 32;       // 1024 / 32
  constexpr int BUF_F = 10240;  // floats per 40KB buffer: in@0 (8192), attT@8192 (2048)
  extern __shared__ float ldsf[];
  const int t = threadIdx.x, lam = t & 63, w = t >> 6;
  const int b = blockIdx.x >> 1, dt = blockIdx.x & 1;
  const int ig = t >> 5, dg = t & 31;
  const float* inb = inputs + (size_t)b * (Nn * Dd) + dt * 256;
  const float* attsrc = attn + (size_t)b * (Ss * Nn) + (size_t)(t >> 2) * Nn + (t & 3) * 8;
  float acc[8][8] = {};
  float4 ga0, ga1, gb0, gb1;

#define UISSUE(bufi, tile, G0, G1)                                        \
  {                                                                       \
    const int j0_ = (tile)*32;                                            \
    G0 = *(const float4*)(attsrc + j0_);                                  \
    G1 = *(const float4*)(attsrc + j0_ + 4);                              \
    float* db_ = ldsf + (bufi)*BUF_F;                                     \
    _Pragma("unroll") for (int i_ = 0; i_ < 8; i_++) {                    \
      const int row_ = i_ * 4 + w;                                        \
      gl_lds16(inb + (size_t)(j0_ + row_) * Dd + lam * 4, db_ + row_ * 256); \
    }                                                                     \
  }

#define UWRITE(bufi, G0, G1)                                              \
  {                                                                       \
    float* ab_ = ldsf + (bufi)*BUF_F + 8192;                              \
    const int col_ = t >> 2;                                              \
    const int r0_ = (t & 3) * 8;                                          \
    ab_[(r0_ + 0) * 64 + col_] = G0.x;                                    \
    ab_[(r0_ + 1) * 64 + col_] = G0.y;                                    \
    ab_[(r0_ + 2) * 64 + col_] = G0.z;                                    \
    ab_[(r0_ + 3) * 64 + col_] = G0.w;                                    \
    ab_[(r0_ + 4) * 64 + col_] = G1.x;                                    \
    ab_[(r0_ + 5) * 64 + col_] = G1.y;                                    \
    ab_[(r0_ + 6) * 64 + col_] = G1.z;                                    \
    ab_[(r0_ + 7) * 64 + col_] = G1.w;                                    \
  }

#define UCOMP(bufi)                                                       \
  {                                                                       \
    const float* db_ = ldsf + (bufi)*BUF_F;                               \
    const float* ab_ = db_ + 8192;                                        \
    _Pragma("unroll 4") for (int jj = 0; jj < 32; jj++) {                 \
      float av[8], vv[8];                                                 \
      *(float4*)&av[0] = *(const float4*)(ab_ + jj * 64 + ig * 8);        \
      *(float4*)&av[4] = *(const float4*)(ab_ + jj * 64 + ig * 8 + 4);    \
      *(float4*)&vv[0] = *(const float4*)(db_ + jj * 256 + dg * 8);       \
      *(float4*)&vv[4] = *(const float4*)(db_ + jj * 256 + dg * 8 + 4);   \
      _Pragma("unroll") for (int m_ = 0; m_ < 8; m_++)                    \
          _Pragma("unroll") for (int n_ = 0; n_ < 8; n_++)                \
              acc[m_][n_] = __builtin_fmaf(av[m_], vv[n_], acc[m_][n_]);  \
    }                                                                     \
  }

  UISSUE(0, 0, ga0, ga1);
  UISSUE(1, 1, gb0, gb1);
  UWRITE(0, ga0, ga1);

  for (int tt = 0; tt < NT2; tt += 2) {
    asm volatile("s_waitcnt vmcnt(10)" ::: "memory");
    UWRITE((tt + 1) % 3, gb0, gb1);
    asm volatile("s_waitcnt lgkmcnt(0)" ::: "memory");
    __builtin_amdgcn_s_barrier();
    __builtin_amdgcn_sched_barrier(0);
    if (tt < NT2 - 2) UISSUE((tt + 2) % 3, tt + 2, ga0, ga1);
    UCOMP(tt % 3);
    if (tt + 1 < NT2 - 1) {
      asm volatile("s_waitcnt vmcnt(10)" ::: "memory");
    } else {
      asm volatile("s_waitcnt vmcnt(0)" ::: "memory");
    }
    if (tt + 1 < NT2 - 1) UWRITE((tt + 2) % 3, ga0, ga1);
    asm volatile("s_waitcnt lgkmcnt(0)" ::: "memory");
    __builtin_amdgcn_s_barrier();
    __builtin_amdgcn_sched_barrier(0);
    if (tt + 1 < NT2 - 2) UISSUE((tt + 3) % 3, tt + 3, gb0, gb1);
    UCOMP((tt + 1) % 3);
  }
#undef UISSUE
#undef UWRITE
#undef UCOMP

#pragma unroll
  for (int m = 0; m < 8; m++) {
    const int i = ig * 8 + m;
    const float ir = inv_r[b * 64 + i];
    float4 o0, o1;
    o0.x = acc[m][0] * ir; o0.y = acc[m][1] * ir; o0.z = acc[m][2] * ir; o0.w = acc[m][3] * ir;
    o1.x = acc[m][4] * ir; o1.y = acc[m][5] * ir; o1.z = acc[m][6] * ir; o1.w = acc[m][7] * ir;
    float* op = out0 + (size_t)(b * 64 + i) * Dd + dt * 256 + dg * 8;
    *(float4*)op = o0;
    *(float4*)(op + 4) = o1;
  }
}

extern "C" void kernel_launch(void* const* d_in, const int* in_sizes, int n_in,
                              void* d_out, int out_size, void* d_ws, size_t ws_size,
                              hipStream_t stream) {
  (void)in_sizes; (void)n_in; (void)out_size; (void)ws_size;
  const float* inputs_pe = (const float*)d_in[0];
  const float* inputs = (const float*)d_in[1];
  const float* slots = (const float*)d_in[2];
  const float* W1 = (const float*)d_in[3];
  const float* b1 = (const float*)d_in[4];
  const float* W2 = (const float*)d_in[5];
  const float* b2 = (const float*)d_in[6];
  const float* W3 = (const float*)d_in[7];
  const float* b3 = (const float*)d_in[8];

  char* ws = (char*)d_ws;
  size_t off = 0;
  auto alloc = [&](size_t bytes) -> void* {
    void* p = ws + off;
    off += (bytes + 255) & ~(size_t)255;
    return p;
  };
  const size_t actB = (size_t)Bb * Nn * Dd * 2;
  unsigned short* Ahi = (unsigned short*)alloc(actB);
  unsigned short* Alo = (unsigned short*)alloc(actB);
  unsigned short* Bhi = (unsigned short*)alloc(actB);
  unsigned short* Blo = (unsigned short*)alloc(actB);
  unsigned short* w1h = (unsigned short*)alloc(Dd * Dd * 2);
  unsigned short* w1l = (unsigned short*)alloc(Dd * Dd * 2);
  unsigned short* w2h = (unsigned short*)alloc(Dd * Dd * 2);
  unsigned short* w2l = (unsigned short*)alloc(Dd * Dd * 2);
  unsigned short* w3h = (unsigned short*)alloc(Dd * Dd * 2);
  unsigned short* w3l = (unsigned short*)alloc(Dd * Dd * 2);
  unsigned short* sh = (unsigned short*)alloc(Ss * Dd * 2);
  unsigned short* sl = (unsigned short*)alloc(Ss * Dd * 2);
  float* dotsb = (float*)alloc((size_t)Bb * Ss * Nn * 4);
  float* s_j = (float*)alloc(Bb * Ss * 4);
  float* s_all = (float*)alloc(Bb * 4);
  float* inv_r = (float*)alloc(Bb * Ss * 4);

  float* out_updates = (float*)d_out;
  float* out_attn = out_updates + (size_t)Bb * Ss * Dd;

  const int kLdsG = 4 * 32 * 1024;  // 128KB ring-4 for gemm_hp
  const int kLdsU = 3 * 40 * 1024;  // 120KB for updates_k2
  hipFuncSetAttribute(reinterpret_cast<const void*>(gemm_hp<1>),
                      hipFuncAttributeMaxDynamicSharedMemorySize, kLdsG);
  hipFuncSetAttribute(reinterpret_cast<const void*>(gemm_hp<0>),
                      hipFuncAttributeMaxDynamicSharedMemorySize, kLdsG);
  hipFuncSetAttribute(reinterpret_cast<const void*>(updates_k2),
                      hipFuncAttributeMaxDynamicSharedMemorySize, kLdsU);

  cast_split<<<4096, 256, 0, stream>>>(inputs_pe, Ahi, Alo, Bb * Nn * Dd / 4);
  cast_split<<<256, 256, 0, stream>>>(W1, w1h, w1l, Dd * Dd / 4);
  cast_split<<<256, 256, 0, stream>>>(W2, w2h, w2l, Dd * Dd / 4);
  cast_split<<<256, 256, 0, stream>>>(W3, w3h, w3l, Dd * Dd / 4);
  cast_split<<<32, 256, 0, stream>>>(slots, sh, sl, Ss * Dd / 4);

  gemm_hp<1><<<1024, 512, kLdsG, stream>>>(Ahi, Alo, w1h, w1l, b1, Bhi, Blo);
  gemm_hp<1><<<1024, 512, kLdsG, stream>>>(Bhi, Blo, w2h, w2l, b2, Ahi, Alo);
  gemm_hp<0><<<1024, 512, kLdsG, stream>>>(Ahi, Alo, w3h, w3l, b3, Bhi, Blo);

  gemm_dots_split<<<Bb * 8, 256, 0, stream>>>(sh, sl, Bhi, Blo, dotsb);
  reduce_k<<<Bb, 256, 0, stream>>>(dotsb, s_j, s_all);
  attn_k<<<Bb * Ss, 256, 0, stream>>>(dotsb, s_j, s_all, out_attn, inv_r);
  updates_k2<<<Bb * 2, 256, kLdsU, stream>>>(out_attn, inputs, inv_r, out_updates);
}

// Round 11
// 1030.193 us; speedup vs baseline: 1.0742x; 1.0742x over previous
//
#include <hip/hip_runtime.h>
#include <stdint.h>

#define Bb 128
#define Nn 1024
#define Dd 512
#define Ss 64

constexpr float kScale = 0.044194173824159216f;  // 512^-0.5
constexpr float kEps = 1e-8f;

typedef __bf16 bf16x8 __attribute__((ext_vector_type(8)));
typedef float f32x4 __attribute__((ext_vector_type(4)));
typedef float f32x16 __attribute__((ext_vector_type(16)));
typedef unsigned short ushort8 __attribute__((ext_vector_type(8)));

#define MFMA32 __builtin_amdgcn_mfma_f32_32x32x16_bf16

__device__ inline unsigned short f2bf_rne(float x) {
  unsigned u = __builtin_bit_cast(unsigned, x);
  u += 0x7FFFu + ((u >> 16) & 1u);
  return (unsigned short)(u >> 16);
}
__device__ inline float bf2f(unsigned short h) {
  unsigned u = ((unsigned)h) << 16;
  return __builtin_bit_cast(float, u);
}

// async global->LDS, 16B per lane; LDS dest must be wave-uniform base (HW adds lane*16)
__device__ inline void gl_lds16(const void* g, void* l) {
  typedef unsigned int u32;
  auto gp = (u32 __attribute__((address_space(1)))*)(unsigned long long)(uintptr_t)g;
  auto lp = (u32 __attribute__((address_space(3)))*)(unsigned int)(uintptr_t)l;
  __builtin_amdgcn_global_load_lds(gp, lp, 16, 0, 0);
}

// f32 -> INTERLEAVED split bf16: out[granule*16 + 0..7] = hi, [+8..15] = lo.
// (granule = 8 consecutive elements; a 64B line = hi_g,lo_g,hi_{g+1},lo_{g+1})
__global__ void cast_split_i(const float* __restrict__ in,
                             unsigned short* __restrict__ out, int n8) {
  int i = blockIdx.x * blockDim.x + threadIdx.x;
  const int stride = gridDim.x * blockDim.x;
  for (; i < n8; i += stride) {
    const float4 v0 = ((const float4*)in)[i * 2];
    const float4 v1 = ((const float4*)in)[i * 2 + 1];
    float f[8] = {v0.x, v0.y, v0.z, v0.w, v1.x, v1.y, v1.z, v1.w};
    ushort8 h, lo;
#pragma unroll
    for (int j = 0; j < 8; j++) {
      h[j] = f2bf_rne(f[j]);
      lo[j] = f2bf_rne(f[j] - bf2f(h[j]));
    }
    ((ushort8*)out)[i * 2] = h;
    ((ushort8*)out)[i * 2 + 1] = lo;
  }
}

// C[M,512] = act(A[M,512] @ W[512,512]^T + bias), FUSED 3-term split bf16.
// All operands/results in INTERLEAVED split layout: [row][1024 ushorts] where
// granule g (k=8g..8g+7) sits at g*16 (+0 hi, +8 lo).
// BM=BN=256, 8 waves (2Mx4N), wave-tile 128x64, 32x32x16 MFMA, K-half = 16.
// Ring-4 x 32KB LDS slots (A[256][32] @0 | W[256][32] @8192 ushorts).
// STAGING (the R10 fix): one gl_lds = 16 rows x one 64B contiguous segment
// (4 lanes/row) — m97 feed granularity; 32B-pair swizzle p2 = g^((row>>2)&1)
// rides inside the segment (source permuted, LDS dest perfectly linear).
// Schedule identical to R9 (race-fixed order): lgkmcnt(0); vmcnt(counted);
// barrier; STG(h+4); READF(h+1); sched_bar; setprio(1) 24 MFMA setprio(0).
template <int ACT>
__global__ __launch_bounds__(512, 1) void gemm_hp(
    const unsigned short* __restrict__ A, const unsigned short* __restrict__ W,
    const float* __restrict__ bias, unsigned short* __restrict__ C) {
  constexpr int NH = 32;  // K=512 / 16
  extern __shared__ unsigned short lds[];  // 4 x 16384 ushorts = 128KB
  const int t = threadIdx.x, l = t & 63, w = t >> 6;
  const int wr = w >> 2, wc = w & 3;

  // bijective XCD-chunked swizzle (1024 = 8 x 128); wg pairs share the A panel
  const int wg = ((blockIdx.x & 7) << 7) + (blockIdx.x >> 3);
  const long rowA0 = (long)(wg >> 1) * 256;
  const int colB0 = (wg & 1) * 256;

  // ---- staging: 32 chunks/slot (16 rows x 64B each); 4 chunks per wave ----
  // lane l: row = cid*16 + (l>>2); src piece = p2s*16 + (l&1)*8 where
  // p2s = ((l>>1)^(l>>4))&1 -> the 4 lanes of a row cover one contiguous 64B
  // segment in permuted order; dst = id*512 + lane*8 (perfectly linear).
  const unsigned short* base8 = (w < 4) ? A + rowA0 * 1024 : W + (long)colB0 * 1024;
  const int p2s = ((l >> 1) ^ (l >> 4)) & 1;
  const unsigned short* srcp[4];
  int dstp[4];
#pragma unroll
  for (int j = 0; j < 4; j++) {
    const int cid = (w & 3) * 4 + j;
    srcp[j] = base8 + (long)(cid * 16 + (l >> 2)) * 1024 + p2s * 16 + (l & 1) * 8;
    dstp[j] = (w * 4 + j) * 512;  // + lane*8 implicit
  }
#define STG(h)                                                            \
  {                                                                       \
    unsigned short* bq_ = lds + ((h) & 3) * 16384;                        \
    _Pragma("unroll") for (int j = 0; j < 4; j++)                         \
        gl_lds16(srcp[j] + (h) * 32, bq_ + dstp[j]);                      \
  }

  // ---- frag reads: row = R0+(l&31), granule g = l>>5;
  // stored pair pos = g ^ ((row>>2)&1) = (l>>5) ^ ((l>>2)&1). hi +0, lo +8. ----
  const int pp16 = (((l >> 5) ^ ((l >> 2) & 1))) * 16;
  const int abase0 = (wr * 128 + (l & 31)) * 32 + pp16;          // A @0
  const int bbase0 = 8192 + (wc * 64 + (l & 31)) * 32 + pp16;    // W @8192

#define READF(h, S)                                                       \
  {                                                                       \
    const unsigned short* bq_ = lds + ((h) & 3) * 16384;                  \
    _Pragma("unroll") for (int m = 0; m < 4; m++) {                       \
      ah##S[m] = *(const bf16x8*)(bq_ + abase0 + m * 1024);               \
      al##S[m] = *(const bf16x8*)(bq_ + abase0 + m * 1024 + 8);           \
    }                                                                     \
    _Pragma("unroll") for (int n = 0; n < 2; n++) {                       \
      bh##S[n] = *(const bf16x8*)(bq_ + bbase0 + n * 1024);               \
      bl##S[n] = *(const bf16x8*)(bq_ + bbase0 + n * 1024 + 8);           \
    }                                                                     \
  }

#define MFMACL(S)                                                         \
  {                                                                       \
    _Pragma("unroll") for (int m = 0; m < 4; m++)                         \
        _Pragma("unroll") for (int n = 0; n < 2; n++) {                   \
      acc[m][n] = MFMA32(ah##S[m], bh##S[n], acc[m][n], 0, 0, 0);         \
      acc[m][n] = MFMA32(al##S[m], bh##S[n], acc[m][n], 0, 0, 0);         \
      acc[m][n] = MFMA32(ah##S[m], bl##S[n], acc[m][n], 0, 0, 0);         \
    }                                                                     \
  }

#define BODY(h, CUR, NXT)                                                 \
  {                                                                       \
    asm volatile("s_waitcnt lgkmcnt(0)" ::: "memory");                    \
    __builtin_amdgcn_sched_barrier(0);                                    \
    if ((h) < 29) {                                                       \
      asm volatile("s_waitcnt vmcnt(8)" ::: "memory");                    \
    } else if ((h) == 29) {                                               \
      asm volatile("s_waitcnt vmcnt(4)" ::: "memory");                    \
    } else if ((h) == 30) {                                               \
      asm volatile("s_waitcnt vmcnt(0)" ::: "memory");                    \
    }                                                                     \
    __builtin_amdgcn_s_barrier();                                         \
    if ((h) + 4 < NH) STG((h) + 4);                                       \
    if ((h) + 1 < NH) READF((h) + 1, NXT);                                \
    __builtin_amdgcn_sched_barrier(0);                                    \
    __builtin_amdgcn_s_setprio(1);                                        \
    MFMACL(CUR);                                                          \
    __builtin_amdgcn_s_setprio(0);                                        \
  }

  f32x16 acc[4][2] = {};
  bf16x8 ahA[4], alA[4], bhA[2], blA[2];
  bf16x8 ahB[4], alB[4], bhB[2], blB[2];

  STG(0); STG(1); STG(2); STG(3);
  asm volatile("s_waitcnt vmcnt(12)" ::: "memory");  // own stage(0) landed
  __builtin_amdgcn_s_barrier();                      // everyone's stage(0) landed
  READF(0, A);

  for (int hh = 0; hh < NH; hh += 2) {
    BODY(hh, A, B);
    BODY(hh + 1, B, A);
  }
#undef STG
#undef READF
#undef MFMACL
#undef BODY

  // epilogue: C/D 32x32 layout: col = l&31, row = (r&3)+8*(r>>2)+4*(l>>5);
  // write interleaved: hi at row*1024 + (col>>3)*16 + (col&7), lo at +8.
#pragma unroll
  for (int m = 0; m < 4; m++)
#pragma unroll
    for (int n = 0; n < 2; n++) {
      const int col = colB0 + wc * 64 + n * 32 + (l & 31);
      const float bv = bias[col];
      const int cofs = (col >> 3) * 16 + (col & 7);
#pragma unroll
      for (int r = 0; r < 16; r++) {
        const long row = rowA0 + wr * 128 + m * 32 + (r & 3) + 8 * (r >> 2) + 4 * (l >> 5);
        float xv = acc[m][n][r] + bv;
        if (ACT) xv = fmaxf(xv, 0.0f);
        const unsigned short h = f2bf_rne(xv);
        unsigned short* cp = C + row * 1024 + cofs;
        cp[0] = h;
        cp[8] = f2bf_rne(xv - bf2f(h));
      }
    }
}

// dots[b,64,1024] = scale * slots[64,512] @ k[b,1024,512]^T
// Q and K inputs in interleaved split layout; LDS/frag structure unchanged.
// R11 fix: B rows 64..127 stage at +2048 ushorts (64 rows x 32), NOT +16384.
__global__ __launch_bounds__(256) void gemm_dots_split(
    const unsigned short* __restrict__ QI, const unsigned short* __restrict__ KI,
    float* __restrict__ dots) {
  constexpr int K = 512, BM = 64, BN = 128, BK = 32;
  __shared__ __align__(16) unsigned short lah[BM * BK];
  __shared__ __align__(16) unsigned short lal[BM * BK];
  __shared__ __align__(16) unsigned short lbh[BN * BK];
  __shared__ __align__(16) unsigned short lbl[BN * BK];
  const int t = threadIdx.x, l = t & 63, w = t >> 6;
  const int b = blockIdx.x >> 3, bc = blockIdx.x & 7;
  const unsigned short* kb = KI + (long)b * Nn * 1024;
  f32x4 acc[4][2] = {};

  // source bases: row stride 1024 ushorts (interleaved); granule (t&3) at (t&3)*16
  const int qbase = (t >> 2) * 1024 + (t & 3) * 16;
  const long kbase0 = (long)(bc * BN + (t >> 2)) * 1024 + (t & 3) * 16;
  const long kbase1 = (long)(bc * BN + 64 + (t >> 2)) * 1024 + (t & 3) * 16;

  for (int k0 = 0; k0 < K; k0 += BK) {
    const int ko = k0 * 2;  // ushort offset of granule (k0>>3)*16
    const int lo = w * 512;
    gl_lds16(QI + qbase + ko, lah + lo);
    gl_lds16(QI + qbase + ko + 8, lal + lo);
    gl_lds16(kb + kbase0 + ko, lbh + lo);
    gl_lds16(kb + kbase0 + ko + 8, lbl + lo);
    gl_lds16(kb + kbase1 + ko, lbh + 2048 + lo);
    gl_lds16(kb + kbase1 + ko + 8, lbl + 2048 + lo);
    __syncthreads();
    bf16x8 ah[4], al[4], bh[2], bl[2];
#pragma unroll
    for (int m = 0; m < 4; m++) {
      const int off = (m * 16 + (l & 15)) * BK + (l >> 4) * 8;
      ah[m] = *(const bf16x8*)(lah + off);
      al[m] = *(const bf16x8*)(lal + off);
    }
#pragma unroll
    for (int n = 0; n < 2; n++) {
      const int off = (w * 32 + n * 16 + (l & 15)) * BK + (l >> 4) * 8;
      bh[n] = *(const bf16x8*)(lbh + off);
      bl[n] = *(const bf16x8*)(lbl + off);
    }
#pragma unroll
    for (int m = 0; m < 4; m++)
#pragma unroll
      for (int n = 0; n < 2; n++) {
        acc[m][n] = __builtin_amdgcn_mfma_f32_16x16x32_bf16(ah[m], bh[n], acc[m][n], 0, 0, 0);
        acc[m][n] = __builtin_amdgcn_mfma_f32_16x16x32_bf16(al[m], bh[n], acc[m][n], 0, 0, 0);
        acc[m][n] = __builtin_amdgcn_mfma_f32_16x16x32_bf16(ah[m], bl[n], acc[m][n], 0, 0, 0);
      }
    __syncthreads();
  }
  float* dp = dots + (long)b * Ss * Nn;
#pragma unroll
  for (int m = 0; m < 4; m++) {
    const int row = m * 16 + (l >> 4) * 4;
#pragma unroll
    for (int n = 0; n < 2; n++) {
      const int col = bc * BN + w * 32 + n * 16 + (l & 15);
#pragma unroll
      for (int r = 0; r < 4; r++) dp[(long)(row + r) * Nn + col] = acc[m][n][r] * kScale;
    }
  }
}

// per-batch: s_j[b,i] = sum_j dots, s_all[b] = sum_ij dots
__global__ __launch_bounds__(256) void reduce_k(
    const float* __restrict__ dots, float* __restrict__ s_j, float* __restrict__ s_all) {
  const int b = blockIdx.x;
  const int t = threadIdx.x;
  const float* dp = dots + (long)b * Ss * Nn;
  const int i = t >> 2, qq = t & 3;
  float s = 0.f;
  const float* rp = dp + i * Nn + qq * 256;
  for (int j = 0; j < 256; j++) s += rp[j];
  __shared__ float part[256];
  __shared__ float rowsum[64];
  part[t] = s;
  __syncthreads();
  if (t < 64) {
    const float v = part[t * 4] + part[t * 4 + 1] + part[t * 4 + 2] + part[t * 4 + 3];
    rowsum[t] = v;
    s_j[b * 64 + t] = v;
  }
  __syncthreads();
  if (t == 0) {
    float tot = 0.f;
    for (int k = 0; k < 64; k++) tot += rowsum[k];
    s_all[b] = tot;
  }
}

// attn = sigmoid(dots * s_all/s_j) -> out; inv_r = 1/(rowsum(attn)+eps)
__global__ __launch_bounds__(256) void attn_k(
    const float* __restrict__ dots, const float* __restrict__ s_j,
    const float* __restrict__ s_all, float* __restrict__ attn_out,
    float* __restrict__ inv_r) {
  const int bi = blockIdx.x;
  const int b = bi >> 6;
  const int t = threadIdx.x;
  const float ratio = s_all[b] / s_j[bi];
  const float* dp = dots + (long)bi * Nn;
  float* ap = attn_out + (long)bi * Nn;
  float s = 0.f;
#pragma unroll
  for (int qq = 0; qq < 4; qq++) {
    const int j = qq * 256 + t;
    const float x = dp[j] * ratio;
    const float a = 1.f / (1.f + expf(-x));
    ap[j] = a;
    s += a;
  }
  __shared__ float red[256];
  red[t] = s;
  __syncthreads();
  for (int off = 128; off > 0; off >>= 1) {
    if (t < off) red[t] += red[t + off];
    __syncthreads();
  }
  if (t == 0) inv_r[bi] = 1.f / (red[0] + kEps);
}

// updates[b,i,d] = inv_r[b,i] * sum_j attn[b,i,j] * inputs[b,j,d]  (fp32 register tile)
__global__ __launch_bounds__(256, 1) void updates_k2(
    const float* __restrict__ attn, const float* __restrict__ inputs,
    const float* __restrict__ inv_r, float* __restrict__ out0) {
  constexpr int NT2 = 32;
  constexpr int BUF_F = 10240;
  extern __shared__ float ldsf[];
  const int t = threadIdx.x, lam = t & 63, w = t >> 6;
  const int b = blockIdx.x >> 1, dt = blockIdx.x & 1;
  const int ig = t >> 5, dg = t & 31;
  const float* inb = inputs + (size_t)b * (Nn * Dd) + dt * 256;
  const float* attsrc = attn + (size_t)b * (Ss * Nn) + (size_t)(t >> 2) * Nn + (t & 3) * 8;
  float acc[8][8] = {};
  float4 ga0, ga1, gb0, gb1;

#define UISSUE(bufi, tile, G0, G1)                                        \
  {                                                                       \
    const int j0_ = (tile)*32;                                            \
    G0 = *(const float4*)(attsrc + j0_);                                  \
    G1 = *(const float4*)(attsrc + j0_ + 4);                              \
    float* db_ = ldsf + (bufi)*BUF_F;                                     \
    _Pragma("unroll") for (int i_ = 0; i_ < 8; i_++) {                    \
      const int row_ = i_ * 4 + w;                                        \
      gl_lds16(inb + (size_t)(j0_ + row_) * Dd + lam * 4, db_ + row_ * 256); \
    }                                                                     \
  }

#define UWRITE(bufi, G0, G1)                                              \
  {                                                                       \
    float* ab_ = ldsf + (bufi)*BUF_F + 8192;                              \
    const int col_ = t >> 2;                                              \
    const int r0_ = (t & 3) * 8;                                          \
    ab_[(r0_ + 0) * 64 + col_] = G0.x;                                    \
    ab_[(r0_ + 1) * 64 + col_] = G0.y;                                    \
    ab_[(r0_ + 2) * 64 + col_] = G0.z;                                    \
    ab_[(r0_ + 3) * 64 + col_] = G0.w;                                    \
    ab_[(r0_ + 4) * 64 + col_] = G1.x;                                    \
    ab_[(r0_ + 5) * 64 + col_] = G1.y;                                    \
    ab_[(r0_ + 6) * 64 + col_] = G1.z;                                    \
    ab_[(r0_ + 7) * 64 + col_] = G1.w;                                    \
  }

#define UCOMP(bufi)                                                       \
  {                                                                       \
    const float* db_ = ldsf + (bufi)*BUF_F;                               \
    const float* ab_ = db_ + 8192;                                        \
    _Pragma("unroll 4") for (int jj = 0; jj < 32; jj++) {                 \
      float av[8], vv[8];                                                 \
      *(float4*)&av[0] = *(const float4*)(ab_ + jj * 64 + ig * 8);        \
      *(float4*)&av[4] = *(const float4*)(ab_ + jj * 64 + ig * 8 + 4);    \
      *(float4*)&vv[0] = *(const float4*)(db_ + jj * 256 + dg * 8);       \
      *(float4*)&vv[4] = *(const float4*)(db_ + jj * 256 + dg * 8 + 4);   \
      _Pragma("unroll") for (int m_ = 0; m_ < 8; m_++)                    \
          _Pragma("unroll") for (int n_ = 0; n_ < 8; n_++)                \
              acc[m_][n_] = __builtin_fmaf(av[m_], vv[n_], acc[m_][n_]);  \
    }                                                                     \
  }

  UISSUE(0, 0, ga0, ga1);
  UISSUE(1, 1, gb0, gb1);
  UWRITE(0, ga0, ga1);

  for (int tt = 0; tt < NT2; tt += 2) {
    asm volatile("s_waitcnt vmcnt(10)" ::: "memory");
    UWRITE((tt + 1) % 3, gb0, gb1);
    asm volatile("s_waitcnt lgkmcnt(0)" ::: "memory");
    __builtin_amdgcn_s_barrier();
    __builtin_amdgcn_sched_barrier(0);
    if (tt < NT2 - 2) UISSUE((tt + 2) % 3, tt + 2, ga0, ga1);
    UCOMP(tt % 3);
    if (tt + 1 < NT2 - 1) {
      asm volatile("s_waitcnt vmcnt(10)" ::: "memory");
    } else {
      asm volatile("s_waitcnt vmcnt(0)" ::: "memory");
    }
    if (tt + 1 < NT2 - 1) UWRITE((tt + 2) % 3, ga0, ga1);
    asm volatile("s_waitcnt lgkmcnt(0)" ::: "memory");
    __builtin_amdgcn_s_barrier();
    __builtin_amdgcn_sched_barrier(0);
    if (tt + 1 < NT2 - 2) UISSUE((tt + 3) % 3, tt + 3, gb0, gb1);
    UCOMP((tt + 1) % 3);
  }
#undef UISSUE
#undef UWRITE
#undef UCOMP

#pragma unroll
  for (int m = 0; m < 8; m++) {
    const int i = ig * 8 + m;
    const float ir = inv_r[b * 64 + i];
    float4 o0, o1;
    o0.x = acc[m][0] * ir; o0.y = acc[m][1] * ir; o0.z = acc[m][2] * ir; o0.w = acc[m][3] * ir;
    o1.x = acc[m][4] * ir; o1.y = acc[m][5] * ir; o1.z = acc[m][6] * ir; o1.w = acc[m][7] * ir;
    float* op = out0 + (size_t)(b * 64 + i) * Dd + dt * 256 + dg * 8;
    *(float4*)op = o0;
    *(float4*)(op + 4) = o1;
  }
}

extern "C" void kernel_launch(void* const* d_in, const int* in_sizes, int n_in,
                              void* d_out, int out_size, void* d_ws, size_t ws_size,
                              hipStream_t stream) {
  (void)in_sizes; (void)n_in; (void)out_size; (void)ws_size;
  const float* inputs_pe = (const float*)d_in[0];
  const float* inputs = (const float*)d_in[1];
  const float* slots = (const float*)d_in[2];
  const float* W1 = (const float*)d_in[3];
  const float* b1 = (const float*)d_in[4];
  const float* W2 = (const float*)d_in[5];
  const float* b2 = (const float*)d_in[6];
  const float* W3 = (const float*)d_in[7];
  const float* b3 = (const float*)d_in[8];

  char* ws = (char*)d_ws;
  size_t off = 0;
  auto alloc = [&](size_t bytes) -> void* {
    void* p = ws + off;
    off += (bytes + 255) & ~(size_t)255;
    return p;
  };
  const size_t actB = (size_t)Bb * Nn * 1024 * 2;  // interleaved split activation
  unsigned short* AI = (unsigned short*)alloc(actB);
  unsigned short* BI = (unsigned short*)alloc(actB);
  unsigned short* w1i = (unsigned short*)alloc(Dd * 1024 * 2);
  unsigned short* w2i = (unsigned short*)alloc(Dd * 1024 * 2);
  unsigned short* w3i = (unsigned short*)alloc(Dd * 1024 * 2);
  unsigned short* qi = (unsigned short*)alloc(Ss * 1024 * 2);
  float* dotsb = (float*)alloc((size_t)Bb * Ss * Nn * 4);
  float* s_j = (float*)alloc(Bb * Ss * 4);
  float* s_all = (float*)alloc(Bb * 4);
  float* inv_r = (float*)alloc(Bb * Ss * 4);

  float* out_updates = (float*)d_out;
  float* out_attn = out_updates + (size_t)Bb * Ss * Dd;

  const int kLdsG = 4 * 32 * 1024;  // 128KB ring-4 for gemm_hp
  const int kLdsU = 3 * 40 * 1024;  // 120KB for updates_k2
  hipFuncSetAttribute(reinterpret_cast<const void*>(gemm_hp<1>),
                      hipFuncAttributeMaxDynamicSharedMemorySize, kLdsG);
  hipFuncSetAttribute(reinterpret_cast<const void*>(gemm_hp<0>),
                      hipFuncAttributeMaxDynamicSharedMemorySize, kLdsG);
  hipFuncSetAttribute(reinterpret_cast<const void*>(updates_k2),
                      hipFuncAttributeMaxDynamicSharedMemorySize, kLdsU);

  cast_split_i<<<4096, 256, 0, stream>>>(inputs_pe, AI, Bb * Nn * Dd / 8);
  cast_split_i<<<128, 256, 0, stream>>>(W1, w1i, Dd * Dd / 8);
  cast_split_i<<<128, 256, 0, stream>>>(W2, w2i, Dd * Dd / 8);
  cast_split_i<<<128, 256, 0, stream>>>(W3, w3i, Dd * Dd / 8);
  cast_split_i<<<16, 256, 0, stream>>>(slots, qi, Ss * Dd / 8);

  gemm_hp<1><<<1024, 512, kLdsG, stream>>>(AI, w1i, b1, BI);
  gemm_hp<1><<<1024, 512, kLdsG, stream>>>(BI, w2i, b2, AI);
  gemm_hp<0><<<1024, 512, kLdsG, stream>>>(AI, w3i, b3, BI);

  gemm_dots_split<<<Bb * 8, 256, 0, stream>>>(qi, BI, dotsb);
  reduce_k<<<Bb, 256, 0, stream>>>(dotsb, s_j, s_all);
  attn_k<<<Bb * Ss, 256, 0, stream>>>(dotsb, s_j, s_all, out_attn, inv_r);
  updates_k2<<<Bb * 2, 256, kLdsU, stream>>>(out_attn, inputs, inv_r, out_updates);
}